// Round 6
// baseline (226.605 us; speedup 1.0000x reference)
//
#include <hip/hip_runtime.h>
#include <math.h>

#define NCLU 10
#define D    64
#define NSLOT 4096

typedef unsigned int   u32;
typedef unsigned short u16;

typedef __attribute__((ext_vector_type(8))) short  bf16x8;
typedef __attribute__((ext_vector_type(4))) float  f32x4;

__device__ __forceinline__ u16 f2bf_rne(float f) {
    u32 u = __float_as_uint(f);
    return (u16)((u + 0x7fffu + ((u >> 16) & 1u)) >> 16);
}

__device__ __forceinline__ bf16x8 pack8(float4 a, float4 b) {
    bf16x8 r;
    r[0] = (short)f2bf_rne(a.x); r[1] = (short)f2bf_rne(a.y);
    r[2] = (short)f2bf_rne(a.z); r[3] = (short)f2bf_rne(a.w);
    r[4] = (short)f2bf_rne(b.x); r[5] = (short)f2bf_rne(b.y);
    r[6] = (short)f2bf_rne(b.z); r[7] = (short)f2bf_rne(b.w);
    return r;
}

__device__ __forceinline__ bf16x8 pack8v(f32x4 a, f32x4 b) {
    bf16x8 r;
    r[0] = (short)f2bf_rne(a[0]); r[1] = (short)f2bf_rne(a[1]);
    r[2] = (short)f2bf_rne(a[2]); r[3] = (short)f2bf_rne(a[3]);
    r[4] = (short)f2bf_rne(b[0]); r[5] = (short)f2bf_rne(b[1]);
    r[6] = (short)f2bf_rne(b[2]); r[7] = (short)f2bf_rne(b[3]);
    return r;
}

__device__ __forceinline__ float wred(float v) {
#pragma unroll
    for (int off = 32; off > 0; off >>= 1) v += __shfl_xor(v, off);
    return v;
}

// Load a 64x64 f32 weight matrix as MFMA A-fragments (bf16): a[mt][kt], lane (quad,lc)
// holds W[16*mt+lc][kt*32 + quad*8 .. +7]. 32 VGPRs total per wave.
__device__ __forceinline__ void load_afrags64(bf16x8 a[4][2], const float* __restrict__ W,
                                              int lc, int quad) {
#pragma unroll
    for (int mt = 0; mt < 4; ++mt)
#pragma unroll
        for (int kt = 0; kt < 2; ++kt) {
            const float* p = W + (16 * mt + lc) * 64 + kt * 32 + quad * 8;
            a[mt][kt] = pack8(*(const float4*)p, *(const float4*)(p + 4));
        }
}

// Same for a 64x128 matrix, covering k-tiles ktbase..ktbase+1 (half of K=128).
__device__ __forceinline__ void load_afrags128(bf16x8 a[4][2], const float* __restrict__ W,
                                               int ktbase, int lc, int quad) {
#pragma unroll
    for (int mt = 0; mt < 4; ++mt)
#pragma unroll
        for (int kt = 0; kt < 2; ++kt) {
            const float* p = W + (16 * mt + lc) * 128 + (ktbase + kt) * 32 + quad * 8;
            a[mt][kt] = pack8(*(const float4*)p, *(const float4*)(p + 4));
        }
}

// B-fragment from f32 LDS state X[n][k] (row stride in floats): lane holds
// X[n=lc][ktglob*32 + quad*8 .. +7], zeros for n>=NCLU.
__device__ __forceinline__ bf16x8 bfrag(const float* __restrict__ xbase, int xstride,
                                        int lc, int quad, int ktglob) {
    if (lc < NCLU) {
        const float* p = xbase + lc * xstride + ktglob * 32 + quad * 8;
        return pack8(*(const float4*)p, *(const float4*)(p + 4));
    }
    bf16x8 z;
#pragma unroll
    for (int j = 0; j < 8; ++j) z[j] = 0;
    return z;
}

// D = A(64xK) @ X^T (+bias from preloaded regs, opt relu) -> out[n=lc][ooff + dim].
// D layout: col=lane&15 (n), row=quad*4+reg (dim within 16-tile).
__device__ __forceinline__ void mm_apply(const bf16x8 a[4][2], const float* __restrict__ xbase,
                                         int xstride, int ktbase,
                                         float* __restrict__ obase, int ostride, int ooff,
                                         const float4 bp[4], bool use_bias, bool do_relu,
                                         int lc, int quad) {
    f32x4 acc[4];
#pragma unroll
    for (int mt = 0; mt < 4; ++mt) acc[mt] = (f32x4){0.f, 0.f, 0.f, 0.f};
#pragma unroll
    for (int kt = 0; kt < 2; ++kt) {
        bf16x8 b = bfrag(xbase, xstride, lc, quad, ktbase + kt);
#pragma unroll
        for (int mt = 0; mt < 4; ++mt)
            acc[mt] = __builtin_amdgcn_mfma_f32_16x16x32_bf16(a[mt][kt], b, acc[mt], 0, 0, 0);
    }
    if (lc < NCLU) {
#pragma unroll
        for (int mt = 0; mt < 4; ++mt) {
            float4 o;
            o.x = acc[mt][0]; o.y = acc[mt][1]; o.z = acc[mt][2]; o.w = acc[mt][3];
            if (use_bias) {
                o.x += bp[mt].x; o.y += bp[mt].y; o.z += bp[mt].z; o.w += bp[mt].w;
            }
            if (do_relu) {
                o.x = fmaxf(o.x, 0.f); o.y = fmaxf(o.y, 0.f);
                o.z = fmaxf(o.z, 0.f); o.w = fmaxf(o.w, 0.f);
            }
            *(float4*)(obase + lc * ostride + ooff + 16 * mt + 4 * quad) = o;
        }
    }
}

// ---------------- Phase 1: MFMA weight-stationary slot-attention ----------------
// (unchanged — it left the top-5 at <43us)
__global__ __launch_bounds__(640, 3) void phase1_kernel(
    const float* __restrict__ cc0,
    const float* __restrict__ Wk, const float* __restrict__ bk,
    const float* __restrict__ Wq, const float* __restrict__ bq,
    const float* __restrict__ Wv, const float* __restrict__ bv,
    const float* __restrict__ cc_g, const float* __restrict__ cc_b,
    const float* __restrict__ W_ih, const float* __restrict__ W_hh,
    const float* __restrict__ b_ih, const float* __restrict__ b_hh,
    const float* __restrict__ ln_g, const float* __restrict__ ln_b,
    const float* __restrict__ W1, const float* __restrict__ b1,
    const float* __restrict__ W2, const float* __restrict__ b2,
    float* __restrict__ cc_out)
{
    const int t = threadIdx.x;
    const int w = t >> 6;
    const int i = t & 63;
    const int quad = i >> 4;
    const int lc   = i & 15;

    __shared__ float ccl[NCLU][68];
    __shared__ float xl[NCLU][68];
    __shared__ float kl[NCLU][68];
    __shared__ float vl[NCLU][68];
    __shared__ float ql[NCLU][68];
    __shared__ float ul[NCLU][68];
    __shared__ float hl[NCLU][68];
    __shared__ float dl9[NCLU][68];
    __shared__ float dl8[NCLU][68];
    __shared__ float tl[NCLU][132];
    __shared__ float gl[6][NCLU][68];
    __shared__ float al[NCLU][12];

    const float g_cc = cc_g[i], b_cc = cc_b[i];
    const float g_ln = ln_g[i], b_ln = ln_b[i];

    bf16x8 afrA[4][2], afrB[4][2];
#pragma unroll
    for (int mt = 0; mt < 4; ++mt)
#pragma unroll
        for (int kt = 0; kt < 2; ++kt) {
#pragma unroll
            for (int j = 0; j < 8; ++j) { afrA[mt][kt][j] = 0; afrB[mt][kt][j] = 0; }
        }

    const float* biasA = nullptr;
    if (w == 0)      { load_afrags64(afrA, Wq, lc, quad);                       biasA = bq; }
    else if (w <= 3) { load_afrags64(afrA, W_ih + (w - 1) * 64 * 64, lc, quad); biasA = b_ih + (w - 1) * 64; }
    else if (w <= 6) { load_afrags64(afrA, W_hh + (w - 4) * 64 * 64, lc, quad); biasA = b_hh + (w - 4) * 64; }
    else if (w == 7) { load_afrags64(afrA, Wk, lc, quad);                       biasA = bk; }
    else if (w == 8) { load_afrags64(afrA, Wv, lc, quad);                       biasA = bv;
                       load_afrags128(afrB, W2, 2, lc, quad); }
    else             { load_afrags128(afrA, W2, 0, lc, quad);                   biasA = b2; }

    float4 bpre[4];
#pragma unroll
    for (int mt = 0; mt < 4; ++mt) { bpre[mt].x = bpre[mt].y = bpre[mt].z = bpre[mt].w = 0.f; }
    if (biasA) {
#pragma unroll
        for (int mt = 0; mt < 4; ++mt) bpre[mt] = *(const float4*)(biasA + 16 * mt + 4 * quad);
    }

    float c = cc0[w * 64 + i];
    ccl[w][i] = c;
    __syncthreads();

    if (w == 7)      mm_apply(afrA, &ccl[0][0], 68, 0, &kl[0][0], 68, 0, bpre, true, false, lc, quad);
    else if (w == 8) mm_apply(afrA, &ccl[0][0], 68, 0, &vl[0][0], 68, 0, bpre, true, false, lc, quad);
    __syncthreads();

    if (w == 7) {
        load_afrags64(afrA, W1, lc, quad);
#pragma unroll
        for (int mt = 0; mt < 4; ++mt) bpre[mt] = *(const float4*)(b1 + 16 * mt + 4 * quad);
    } else if (w == 8) {
        load_afrags64(afrA, W1 + 64 * 64, lc, quad);
#pragma unroll
        for (int mt = 0; mt < 4; ++mt) bpre[mt] = *(const float4*)(b1 + 64 + 16 * mt + 4 * quad);
    }

    for (int it = 0; it < 3; ++it) {
        {
            float s1 = wred(c), s2 = wred(c * c);
            float mu = s1 * (1.f / 64.f);
            float va = s2 * (1.f / 64.f) - mu * mu;
            xl[w][i] = (c - mu) * rsqrtf(va + 1e-5f) * g_cc + b_cc;
        }
        __syncthreads();                                        // bar 1

        if (w == 0)
            mm_apply(afrA, &xl[0][0], 68, 0, &ql[0][0], 68, 0, bpre, true, false, lc, quad);
        else if (w >= 4 && w <= 6)
            mm_apply(afrA, &ccl[0][0], 68, 0, &gl[w - 1][0][0], 68, 0, bpre, true, false, lc, quad);
        __syncthreads();                                        // bar 2

        if (i < NCLU) {
            const float4* kf = (const float4*)&kl[w][0];
            const float4* qf = (const float4*)&ql[i][0];
            float a0 = 0.f, a1 = 0.f, a2 = 0.f, a3 = 0.f;
#pragma unroll
            for (int jj = 0; jj < 16; ++jj) {
                float4 kv = kf[jj], qv = qf[jj];
                a0 += kv.x * qv.x; a1 += kv.y * qv.y; a2 += kv.z * qv.z; a3 += kv.w * qv.w;
            }
            al[w][i] = ((a0 + a1) + (a2 + a3)) * 0.125f;
        }
        __syncthreads();                                        // bar 3

        {
            float e[NCLU];
            if (i < NCLU) {
                float mx = -1e30f;
#pragma unroll
                for (int nn = 0; nn < NCLU; ++nn) mx = fmaxf(mx, al[nn][i]);
                float s = 0.f;
#pragma unroll
                for (int nn = 0; nn < NCLU; ++nn) { e[nn] = __expf(al[nn][i] - mx); s += e[nn]; }
                float inv = 1.f / s;
#pragma unroll
                for (int nn = 0; nn < NCLU; ++nn) e[nn] = e[nn] * inv + 1e-8f;
            } else {
#pragma unroll
                for (int nn = 0; nn < NCLU; ++nn) e[nn] = 0.f;
            }
            float rs[NCLU];
#pragma unroll
            for (int nn = 0; nn < NCLU; ++nn) rs[nn] = e[nn];
#pragma unroll
            for (int off = 1; off < 16; off <<= 1) {
#pragma unroll
                for (int nn = 0; nn < NCLU; ++nn) rs[nn] += __shfl_xor(rs[nn], off);
            }
            float ew = 0.f, rw = 1.f;
#pragma unroll
            for (int nn = 0; nn < NCLU; ++nn) if (nn == w) { ew = e[nn]; rw = rs[nn]; }
            float val = (i < NCLU) ? ew / rw : 0.f;
            float u = 0.f;
#pragma unroll
            for (int m = 0; m < NCLU; ++m) u += __shfl(val, m) * vl[m][i];
            ul[w][i] = u;
        }
        __syncthreads();                                        // bar 4

        if (w >= 1 && w <= 3)
            mm_apply(afrA, &ul[0][0], 68, 0, &gl[w - 1][0][0], 68, 0, bpre, true, false, lc, quad);
        __syncthreads();                                        // bar 5

        {
            float ir = gl[0][w][i], iz = gl[1][w][i], inn = gl[2][w][i];
            float hr = gl[3][w][i], hz = gl[4][w][i], hn = gl[5][w][i];
            float r = 1.f / (1.f + __expf(-(ir + hr)));
            float z = 1.f / (1.f + __expf(-(iz + hz)));
            float xt = inn + r * hn;
            float ex2 = __expf(2.f * xt);
            float nn2 = 1.f - 2.f / (ex2 + 1.f);
            c = (1.f - z) * nn2 + z * c;

            float s1 = wred(c), s2 = wred(c * c);
            float mu = s1 * (1.f / 64.f);
            float va = s2 * (1.f / 64.f) - mu * mu;
            hl[w][i] = (c - mu) * rsqrtf(va + 1e-5f) * g_ln + b_ln;
        }
        __syncthreads();                                        // bar 6

        if (w == 7)
            mm_apply(afrA, &hl[0][0], 68, 0, &tl[0][0], 132, 0, bpre, true, true, lc, quad);
        else if (w == 8)
            mm_apply(afrA, &hl[0][0], 68, 0, &tl[0][0], 132, 64, bpre, true, true, lc, quad);
        __syncthreads();                                        // bar 7

        if (w == 9)
            mm_apply(afrA, &tl[0][0], 132, 0, &dl9[0][0], 68, 0, bpre, true, false, lc, quad);
        else if (w == 8)
            mm_apply(afrB, &tl[0][0], 132, 2, &dl8[0][0], 68, 0, bpre, false, false, lc, quad);
        __syncthreads();                                        // bar 8

        c += dl9[w][i] + dl8[w][i];
        ccl[w][i] = c;
    }

    cc_out[w * 64 + i] = c;
}

// ---------------- Phase 2: inline-asm counted-vmcnt pipelined MLP+max ----------------
// Round 11: the T4 mechanism, finally for real. Evidence R0-R5: five structures all
// ~43-50us at ~3 TB/s; VGPR counts (48/52/56) prove hipcc re-sank every source-level
// prefetch, and __syncthreads' implicit vmcnt(0) drained whatever survived. This
// version takes both away from the compiler:
//  - weight/bias loads are asm volatile global_load_dwordx4 (invisible to the
//    waitcnt pass -> cannot be sunk or drained)
//  - per slot: ISSUE(next 9 loads) then "s_waitcnt vmcnt(9)" with the CURRENT bank
//    as "+v" tied operands (true dataflow ordering); last slot vmcnt(0)
//  - h-exchange barrier = "s_waitcnt lgkmcnt(0); s_barrier" (NO vmcnt drain)
//  - stores deferred to epilogue so vmcnt instruction counts stay exact
// 512 blocks x 8 slots x 4 coop waves; all-resident (launch_bounds min 2 blk/CU).
#define HSTR 72
#define SLOTS_PER_BLK 8

#define P2_ISSUE(jj, bk) do {                                                          \
    const float* _p = pa + (size_t)(jj) * 4096;                                        \
    const float* _q = pb + (size_t)(jj) * 4096;                                        \
    const float* _r = pba + (size_t)(jj) * 64;                                         \
    asm volatile("global_load_dwordx4 %0, %1, off"            : "=v"(rA[bk][0]) : "v"(_p)); \
    asm volatile("global_load_dwordx4 %0, %1, off offset:16"  : "=v"(rA[bk][1]) : "v"(_p)); \
    asm volatile("global_load_dwordx4 %0, %1, off offset:128" : "=v"(rA[bk][2]) : "v"(_p)); \
    asm volatile("global_load_dwordx4 %0, %1, off offset:144" : "=v"(rA[bk][3]) : "v"(_p)); \
    asm volatile("global_load_dwordx4 %0, %1, off"            : "=v"(rB[bk][0]) : "v"(_q)); \
    asm volatile("global_load_dwordx4 %0, %1, off offset:16"  : "=v"(rB[bk][1]) : "v"(_q)); \
    asm volatile("global_load_dwordx4 %0, %1, off offset:128" : "=v"(rB[bk][2]) : "v"(_q)); \
    asm volatile("global_load_dwordx4 %0, %1, off offset:144" : "=v"(rB[bk][3]) : "v"(_q)); \
    asm volatile("global_load_dwordx4 %0, %1, off"            : "=v"(bav[bk])   : "v"(_r)); \
} while (0)

#define P2_WAIT(imm, bk)                                                               \
    asm volatile("s_waitcnt vmcnt(" #imm ")"                                           \
        : "+v"(rA[bk][0]), "+v"(rA[bk][1]), "+v"(rA[bk][2]), "+v"(rA[bk][3]),          \
          "+v"(rB[bk][0]), "+v"(rB[bk][1]), "+v"(rB[bk][2]), "+v"(rB[bk][3]),          \
          "+v"(bav[bk]) :: )

__global__ __launch_bounds__(256, 2) void phase2_kernel(
    const float* __restrict__ Wa, const float* __restrict__ ba,
    const float* __restrict__ Wb, const float* __restrict__ bb,
    const float* __restrict__ cc, float* __restrict__ out)
{
    const int w = threadIdx.x >> 6;       // wave id = output-row stripe 16w..16w+15
    const int l = threadIdx.x & 63;
    const int quad = l >> 4;
    const int lc   = l & 15;
    const int s0 = blockIdx.x * SLOTS_PER_BLK;

    __shared__ u16 hT[2][16 * HSTR];      // ping-pong h-transpose slabs

    // ---- prologue: compiler-managed loads, force-drained BEFORE the asm stream ----
    float4 c00, c01, c10, c11;
    if (lc < NCLU) {
        const float* cp = cc + lc * 64;
        c00 = *(const float4*)(cp + 0 * 32 + quad * 8);
        c01 = *(const float4*)(cp + 0 * 32 + quad * 8 + 4);
        c10 = *(const float4*)(cp + 1 * 32 + quad * 8);
        c11 = *(const float4*)(cp + 1 * 32 + quad * 8 + 4);
    }
    float bbs[SLOTS_PER_BLK];
    if (lc < 4) {
#pragma unroll
        for (int j = 0; j < SLOTS_PER_BLK; ++j)
            bbs[j] = bb[(s0 + j) * 64 + 16 * w + 4 * quad + lc];
    }

    bf16x8 bcc[2];
    if (lc < NCLU) {
        bcc[0] = pack8(c00, c01);
        bcc[1] = pack8(c10, c11);
    } else {
#pragma unroll
        for (int j = 0; j < 8; ++j) { bcc[0][j] = 0; bcc[1][j] = 0; }
    }
    // force bbs waits to land here (prologue), not inside the pipelined loop
#pragma unroll
    for (int j = 0; j < SLOTS_PER_BLK; ++j) asm volatile("" :: "v"(bbs[j]));

    // lane-varying base pointers (stride per slot: 4096 floats / 64 floats)
    const float* pa  = Wa + (size_t)s0 * 4096 + (16 * w + lc) * 64 + quad * 8;
    const float* pb  = Wb + (size_t)s0 * 4096 + (16 * w + lc) * 64 + quad * 8;
    const float* pba = ba + (size_t)s0 * 64 + 16 * w + quad * 4;

    f32x4 rA[2][4], rB[2][4], bav[2];
    float outv[SLOTS_PER_BLK];

    P2_ISSUE(0, 0);                       // prime the pipe: slot 0 in flight

#pragma unroll
    for (int j = 0; j < SLOTS_PER_BLK; ++j) {
        const int cur = j & 1;
        const int nxt = cur ^ 1;

        if (j + 1 < SLOTS_PER_BLK) {
            P2_ISSUE(j + 1, nxt);         // 9 new loads join the queue (18 outstanding)
            P2_WAIT(9, cur);              // drain current bank only; next stays in flight
        } else {
            P2_WAIT(0, cur);              // last slot: full drain
        }

        // pack current fragments
        bf16x8 frA[2], frB[2];
        frA[0] = pack8v(rA[cur][0], rA[cur][1]);
        frA[1] = pack8v(rA[cur][2], rA[cur][3]);
        frB[0] = pack8v(rB[cur][0], rB[cur][1]);
        frB[1] = pack8v(rB[cur][2], rB[cur][3]);

        // matmul1: h stripe = relu(Wa[16w..16w+15,:] @ cc^T + ba stripe)
        f32x4 acc = (f32x4){0.f, 0.f, 0.f, 0.f};
        acc = __builtin_amdgcn_mfma_f32_16x16x32_bf16(frA[0], bcc[0], acc, 0, 0, 0);
        acc = __builtin_amdgcn_mfma_f32_16x16x32_bf16(frA[1], bcc[1], acc, 0, 0, 0);

        // bias + relu + bf16, transpose into ping-pong slab
        {
            u16 h0 = f2bf_rne(fmaxf(acc[0] + bav[cur][0], 0.f));
            u16 h1 = f2bf_rne(fmaxf(acc[1] + bav[cur][1], 0.f));
            u16 h2 = f2bf_rne(fmaxf(acc[2] + bav[cur][2], 0.f));
            u16 h3 = f2bf_rne(fmaxf(acc[3] + bav[cur][3], 0.f));
            uint2 pk; pk.x = (u32)h0 | ((u32)h1 << 16); pk.y = (u32)h2 | ((u32)h3 << 16);
            *(uint2*)(&hT[cur][lc * HSTR + 16 * w + quad * 4]) = pk;
        }

        // LDS-only barrier: ds_writes visible, vmem queue UNTOUCHED
        asm volatile("s_waitcnt lgkmcnt(0)\n\ts_barrier" ::: "memory");

        bf16x8 bh[2];
#pragma unroll
        for (int kt = 0; kt < 2; ++kt)
            bh[kt] = *(const bf16x8*)(&hT[cur][lc * HSTR + kt * 32 + quad * 8]);

        // matmul2: out stripe = Wb[16w..16w+15,:] @ h^T
        f32x4 acc2 = (f32x4){0.f, 0.f, 0.f, 0.f};
        acc2 = __builtin_amdgcn_mfma_f32_16x16x32_bf16(frB[0], bh[0], acc2, 0, 0, 0);
        acc2 = __builtin_amdgcn_mfma_f32_16x16x32_bf16(frB[1], bh[1], acc2, 0, 0, 0);

        // max over clusters (cols lc<NCLU)
        const float NEG = -3.0e38f;
#pragma unroll
        for (int r = 0; r < 4; ++r) {
            float v = (lc < NCLU) ? acc2[r] : NEG;
#pragma unroll
            for (int off = 1; off < 16; off <<= 1)
                v = fmaxf(v, __shfl_xor(v, off));
            acc2[r] = v;
        }
        float ov = (lc == 0) ? acc2[0] : (lc == 1) ? acc2[1] : (lc == 2) ? acc2[2] : acc2[3];
        outv[j] = ov + ((lc < 4) ? bbs[j] : 0.f);
        // slab reuse safety: slot j+2 rewrites slab[cur] only after barrier j+1, by
        // which point all waves' slot-j reads (lgkm-consumed before that barrier)
        // are complete -> 1 barrier/slot suffices.
    }

    // ---- epilogue: all stores (kept out of the loop so vmcnt counts stay exact) ----
    if (lc < 4) {
        const int row = 16 * w + 4 * quad + lc;
#pragma unroll
        for (int j = 0; j < SLOTS_PER_BLK; ++j)
            out[(s0 + j) * 64 + row] = outv[j];
    }
}

extern "C" void kernel_launch(void* const* d_in, const int* in_sizes, int n_in,
                              void* d_out, int out_size, void* d_ws, size_t ws_size,
                              hipStream_t stream) {
    const float* cc0  = (const float*)d_in[0];
    const float* Wk   = (const float*)d_in[1];
    const float* bk   = (const float*)d_in[2];
    const float* Wq   = (const float*)d_in[3];
    const float* bq   = (const float*)d_in[4];
    const float* Wv   = (const float*)d_in[5];
    const float* bv   = (const float*)d_in[6];
    const float* ccg  = (const float*)d_in[7];
    const float* ccb  = (const float*)d_in[8];
    const float* Wih  = (const float*)d_in[9];
    const float* Whh  = (const float*)d_in[10];
    const float* bih  = (const float*)d_in[11];
    const float* bhh  = (const float*)d_in[12];
    const float* lng  = (const float*)d_in[13];
    const float* lnb  = (const float*)d_in[14];
    const float* W1   = (const float*)d_in[15];
    const float* b1   = (const float*)d_in[16];
    const float* W2   = (const float*)d_in[17];
    const float* b2   = (const float*)d_in[18];
    const float* Wa   = (const float*)d_in[19];
    const float* ba   = (const float*)d_in[20];
    const float* Wb   = (const float*)d_in[21];
    const float* bb   = (const float*)d_in[22];

    float* cc_ws = (float*)d_ws;     // 640 floats
    float* out   = (float*)d_out;

    hipLaunchKernelGGL(phase1_kernel, dim3(1), dim3(640), 0, stream,
                       cc0, Wk, bk, Wq, bq, Wv, bv, ccg, ccb,
                       Wih, Whh, bih, bhh, lng, lnb, W1, b1, W2, b2, cc_ws);

    hipLaunchKernelGGL(phase2_kernel, dim3(NSLOT / SLOTS_PER_BLK), dim3(256), 0, stream,
                       Wa, ba, Wb, bb, cc_ws, out);
}

// Round 9
// 214.661 us; speedup vs baseline: 1.0556x; 1.0556x over previous
//
#include <hip/hip_runtime.h>
#include <math.h>

#define NCLU 10
#define D    64
#define NSLOT 4096

typedef unsigned int   u32;
typedef unsigned short u16;

typedef __attribute__((ext_vector_type(8))) short  bf16x8;
typedef __attribute__((ext_vector_type(4))) float  f32x4;

__device__ __forceinline__ u16 f2bf_rne(float f) {
    u32 u = __float_as_uint(f);
    return (u16)((u + 0x7fffu + ((u >> 16) & 1u)) >> 16);
}

__device__ __forceinline__ bf16x8 pack8(float4 a, float4 b) {
    bf16x8 r;
    r[0] = (short)f2bf_rne(a.x); r[1] = (short)f2bf_rne(a.y);
    r[2] = (short)f2bf_rne(a.z); r[3] = (short)f2bf_rne(a.w);
    r[4] = (short)f2bf_rne(b.x); r[5] = (short)f2bf_rne(b.y);
    r[6] = (short)f2bf_rne(b.z); r[7] = (short)f2bf_rne(b.w);
    return r;
}

__device__ __forceinline__ float wred(float v) {
#pragma unroll
    for (int off = 32; off > 0; off >>= 1) v += __shfl_xor(v, off);
    return v;
}

// Load a 64x64 f32 weight matrix as MFMA A-fragments (bf16): a[mt][kt], lane (quad,lc)
// holds W[16*mt+lc][kt*32 + quad*8 .. +7]. 32 VGPRs total per wave.
__device__ __forceinline__ void load_afrags64(bf16x8 a[4][2], const float* __restrict__ W,
                                              int lc, int quad) {
#pragma unroll
    for (int mt = 0; mt < 4; ++mt)
#pragma unroll
        for (int kt = 0; kt < 2; ++kt) {
            const float* p = W + (16 * mt + lc) * 64 + kt * 32 + quad * 8;
            a[mt][kt] = pack8(*(const float4*)p, *(const float4*)(p + 4));
        }
}

// Same for a 64x128 matrix, covering k-tiles ktbase..ktbase+1 (half of K=128).
__device__ __forceinline__ void load_afrags128(bf16x8 a[4][2], const float* __restrict__ W,
                                               int ktbase, int lc, int quad) {
#pragma unroll
    for (int mt = 0; mt < 4; ++mt)
#pragma unroll
        for (int kt = 0; kt < 2; ++kt) {
            const float* p = W + (16 * mt + lc) * 128 + (ktbase + kt) * 32 + quad * 8;
            a[mt][kt] = pack8(*(const float4*)p, *(const float4*)(p + 4));
        }
}

// B-fragment from f32 LDS state X[n][k] (row stride in floats): lane holds
// X[n=lc][ktglob*32 + quad*8 .. +7], zeros for n>=NCLU.
__device__ __forceinline__ bf16x8 bfrag(const float* __restrict__ xbase, int xstride,
                                        int lc, int quad, int ktglob) {
    if (lc < NCLU) {
        const float* p = xbase + lc * xstride + ktglob * 32 + quad * 8;
        return pack8(*(const float4*)p, *(const float4*)(p + 4));
    }
    bf16x8 z;
#pragma unroll
    for (int j = 0; j < 8; ++j) z[j] = 0;
    return z;
}

// D = A(64xK) @ X^T (+bias, opt relu) written to out[n=lc][ooff + dim].
// D layout: col=lane&15 (n), row=quad*4+reg (dim within 16-tile).
__device__ __forceinline__ void mm_apply(const bf16x8 a[4][2], const float* __restrict__ xbase,
                                         int xstride, int ktbase,
                                         float* __restrict__ obase, int ostride, int ooff,
                                         const float* __restrict__ bias, bool do_relu,
                                         int lc, int quad) {
    f32x4 acc[4];
#pragma unroll
    for (int mt = 0; mt < 4; ++mt) acc[mt] = (f32x4){0.f, 0.f, 0.f, 0.f};
#pragma unroll
    for (int kt = 0; kt < 2; ++kt) {
        bf16x8 b = bfrag(xbase, xstride, lc, quad, ktbase + kt);
#pragma unroll
        for (int mt = 0; mt < 4; ++mt)
            acc[mt] = __builtin_amdgcn_mfma_f32_16x16x32_bf16(a[mt][kt], b, acc[mt], 0, 0, 0);
    }
    if (lc < NCLU) {
#pragma unroll
        for (int mt = 0; mt < 4; ++mt) {
            float4 o;
            o.x = acc[mt][0]; o.y = acc[mt][1]; o.z = acc[mt][2]; o.w = acc[mt][3];
            if (bias) {
                float4 bv = *(const float4*)(bias + 16 * mt + 4 * quad);
                o.x += bv.x; o.y += bv.y; o.z += bv.z; o.w += bv.w;
            }
            if (do_relu) {
                o.x = fmaxf(o.x, 0.f); o.y = fmaxf(o.y, 0.f);
                o.z = fmaxf(o.z, 0.f); o.w = fmaxf(o.w, 0.f);
            }
            *(float4*)(obase + lc * ostride + ooff + 16 * mt + 4 * quad) = o;
        }
    }
}

// ---------------- Phase 1: MFMA weight-stationary slot-attention ----------------
// Measured-best configuration (214.06 us total). 1 block x 640 threads = 10 waves.
__global__ __launch_bounds__(640, 3) void phase1_kernel(
    const float* __restrict__ cc0,
    const float* __restrict__ Wk, const float* __restrict__ bk,
    const float* __restrict__ Wq, const float* __restrict__ bq,
    const float* __restrict__ Wv, const float* __restrict__ bv,
    const float* __restrict__ cc_g, const float* __restrict__ cc_b,
    const float* __restrict__ W_ih, const float* __restrict__ W_hh,
    const float* __restrict__ b_ih, const float* __restrict__ b_hh,
    const float* __restrict__ ln_g, const float* __restrict__ ln_b,
    const float* __restrict__ W1, const float* __restrict__ b1,
    const float* __restrict__ W2, const float* __restrict__ b2,
    float* __restrict__ cc_out)
{
    const int t = threadIdx.x;
    const int w = t >> 6;
    const int i = t & 63;
    const int quad = i >> 4;
    const int lc   = i & 15;

    __shared__ float ccl[NCLU][68];
    __shared__ float xl[NCLU][68];
    __shared__ float kl[NCLU][68];
    __shared__ float vl[NCLU][68];
    __shared__ float ql[NCLU][68];
    __shared__ float ul[NCLU][68];
    __shared__ float hl[NCLU][68];
    __shared__ float dl9[NCLU][68];
    __shared__ float dl8[NCLU][68];
    __shared__ float tl[NCLU][132];
    __shared__ float gl[6][NCLU][68];
    __shared__ float al[NCLU][12];

    const float g_cc = cc_g[i], b_cc = cc_b[i];
    const float g_ln = ln_g[i], b_ln = ln_b[i];

    bf16x8 afrA[4][2], afrB[4][2];
#pragma unroll
    for (int mt = 0; mt < 4; ++mt)
#pragma unroll
        for (int kt = 0; kt < 2; ++kt) {
#pragma unroll
            for (int j = 0; j < 8; ++j) { afrA[mt][kt][j] = 0; afrB[mt][kt][j] = 0; }
        }

    const float* biasA = nullptr;
    if (w == 0)      { load_afrags64(afrA, Wq, lc, quad);                    biasA = bq; }
    else if (w <= 3) { load_afrags64(afrA, W_ih + (w - 1) * 64 * 64, lc, quad); biasA = b_ih + (w - 1) * 64; }
    else if (w <= 6) { load_afrags64(afrA, W_hh + (w - 4) * 64 * 64, lc, quad); biasA = b_hh + (w - 4) * 64; }
    else if (w == 7) { load_afrags64(afrA, Wk, lc, quad); }
    else if (w == 8) { load_afrags64(afrA, Wv, lc, quad);
                       load_afrags128(afrB, W2, 2, lc, quad); }
    else             { load_afrags128(afrA, W2, 0, lc, quad); biasA = b2; }

    float c = cc0[w * 64 + i];
    ccl[w][i] = c;
    __syncthreads();

    if (w == 7)      mm_apply(afrA, &ccl[0][0], 68, 0, &kl[0][0], 68, 0, bk, false, lc, quad);
    else if (w == 8) mm_apply(afrA, &ccl[0][0], 68, 0, &vl[0][0], 68, 0, bv, false, lc, quad);
    __syncthreads();

    if (w == 7)      { load_afrags64(afrA, W1, lc, quad);            biasA = b1; }
    else if (w == 8) { load_afrags64(afrA, W1 + 64 * 64, lc, quad);  biasA = b1 + 64; }

    for (int it = 0; it < 3; ++it) {
        {
            float s1 = wred(c), s2 = wred(c * c);
            float mu = s1 * (1.f / 64.f);
            float va = s2 * (1.f / 64.f) - mu * mu;
            xl[w][i] = (c - mu) * rsqrtf(va + 1e-5f) * g_cc + b_cc;
        }
        __syncthreads();

        if (w == 0)
            mm_apply(afrA, &xl[0][0], 68, 0, &ql[0][0], 68, 0, biasA, false, lc, quad);
        else if (w >= 4 && w <= 6)
            mm_apply(afrA, &ccl[0][0], 68, 0, &gl[w - 1][0][0], 68, 0, biasA, false, lc, quad);
        __syncthreads();

        if (i < NCLU) {
            const float4* kf = (const float4*)&kl[w][0];
            const float4* qf = (const float4*)&ql[i][0];
            float a0 = 0.f, a1 = 0.f, a2 = 0.f, a3 = 0.f;
#pragma unroll
            for (int jj = 0; jj < 16; ++jj) {
                float4 kv = kf[jj], qv = qf[jj];
                a0 += kv.x * qv.x; a1 += kv.y * qv.y; a2 += kv.z * qv.z; a3 += kv.w * qv.w;
            }
            al[w][i] = ((a0 + a1) + (a2 + a3)) * 0.125f;
        }
        __syncthreads();

        if (t < NCLU) {
            float mx = -1e30f;
#pragma unroll
            for (int nn = 0; nn < NCLU; ++nn) mx = fmaxf(mx, al[nn][t]);
            float e[NCLU]; float s = 0.f;
#pragma unroll
            for (int nn = 0; nn < NCLU; ++nn) { e[nn] = __expf(al[nn][t] - mx); s += e[nn]; }
            float inv = 1.f / s;
#pragma unroll
            for (int nn = 0; nn < NCLU; ++nn) al[nn][t] = e[nn] * inv + 1e-8f;
        }
        __syncthreads();
        if (t < NCLU) {
            float s = 0.f;
#pragma unroll
            for (int m = 0; m < NCLU; ++m) s += al[t][m];
            float inv = 1.f / s;
#pragma unroll
            for (int m = 0; m < NCLU; ++m) al[t][m] *= inv;
        }
        __syncthreads();

        {
            float u = 0.f;
#pragma unroll
            for (int m = 0; m < NCLU; ++m) u += al[w][m] * vl[m][i];
            ul[w][i] = u;
        }
        __syncthreads();

        if (w >= 1 && w <= 3)
            mm_apply(afrA, &ul[0][0], 68, 0, &gl[w - 1][0][0], 68, 0, biasA, false, lc, quad);
        __syncthreads();

        {
            float ir = gl[0][w][i], iz = gl[1][w][i], inn = gl[2][w][i];
            float hr = gl[3][w][i], hz = gl[4][w][i], hn = gl[5][w][i];
            float r = 1.f / (1.f + __expf(-(ir + hr)));
            float z = 1.f / (1.f + __expf(-(iz + hz)));
            float nn2 = tanhf(inn + r * hn);
            c = (1.f - z) * nn2 + z * c;

            float s1 = wred(c), s2 = wred(c * c);
            float mu = s1 * (1.f / 64.f);
            float va = s2 * (1.f / 64.f) - mu * mu;
            hl[w][i] = (c - mu) * rsqrtf(va + 1e-5f) * g_ln + b_ln;
        }
        __syncthreads();

        if (w == 7)
            mm_apply(afrA, &hl[0][0], 68, 0, &tl[0][0], 132, 0, biasA, true, lc, quad);
        else if (w == 8)
            mm_apply(afrA, &hl[0][0], 68, 0, &tl[0][0], 132, 64, biasA, true, lc, quad);
        __syncthreads();

        if (w == 9)
            mm_apply(afrA, &tl[0][0], 132, 0, &dl9[0][0], 68, 0, biasA, false, lc, quad);
        else if (w == 8)
            mm_apply(afrB, &tl[0][0], 132, 2, &dl8[0][0], 68, 0, nullptr, false, lc, quad);
        __syncthreads();

        c += dl9[w][i] + dl8[w][i];
        ccl[w][i] = c;
        __syncthreads();
    }

    cc_out[w * 64 + i] = c;
}

// ---------------- Phase 2: bf16-MFMA per-slot MLP + max over clusters ----------------
// 4 COOPERATING waves per slot (block = 1 slot, 256 threads). Per-wave footprint is
// its 16-row output stripe: 4 Wa loads + 4 Wb loads + cc + bias all fit in registers
// and issue before any wait. Cross-wave h exchange through shared hT (one barrier).
// Measured-best phase2 (part of the 214.06 us configuration).
#define HSTR 72
__global__ __launch_bounds__(256, 5) void phase2_kernel(
    const float* __restrict__ Wa, const float* __restrict__ ba,
    const float* __restrict__ Wb, const float* __restrict__ bb,
    const float* __restrict__ cc, float* __restrict__ out)
{
    const int w = threadIdx.x >> 6;       // wave id = output-row stripe 16w..16w+15
    const int l = threadIdx.x & 63;
    const int s = blockIdx.x;             // slot
    const int quad = l >> 4;
    const int lc   = l & 15;

    __shared__ u16 hT[16 * HSTR];         // h transposed: [n][dim] bf16, shared by 4 waves

    const float* wa = Wa + (size_t)s * 4096;
    const float* wb = Wb + (size_t)s * 4096;

    // ---- issue ALL global loads up front ----
    float4 c00, c01, c10, c11;
    if (lc < NCLU) {
        const float* cp = cc + lc * 64;
        c00 = *(const float4*)(cp + 0 * 32 + quad * 8);
        c01 = *(const float4*)(cp + 0 * 32 + quad * 8 + 4);
        c10 = *(const float4*)(cp + 1 * 32 + quad * 8);
        c11 = *(const float4*)(cp + 1 * 32 + quad * 8 + 4);
    }
    float4 a00, a01, a10, a11;
    {
        const float* p0 = wa + (16 * w + lc) * 64 + 0 * 32 + quad * 8;
        const float* p1 = wa + (16 * w + lc) * 64 + 1 * 32 + quad * 8;
        a00 = *(const float4*)p0; a01 = *(const float4*)(p0 + 4);
        a10 = *(const float4*)p1; a11 = *(const float4*)(p1 + 4);
    }
    float4 bav = *(const float4*)(ba + s * 64 + 16 * w + quad * 4);
    float4 b00, b01, b10, b11;
    {
        const float* p0 = wb + (16 * w + lc) * 64 + 0 * 32 + quad * 8;
        const float* p1 = wb + (16 * w + lc) * 64 + 1 * 32 + quad * 8;
        b00 = *(const float4*)p0; b01 = *(const float4*)(p0 + 4);
        b10 = *(const float4*)p1; b11 = *(const float4*)(p1 + 4);
    }

    bf16x8 frA[2];
    frA[0] = pack8(a00, a01);
    frA[1] = pack8(a10, a11);
    bf16x8 bcc[2];
    if (lc < NCLU) {
        bcc[0] = pack8(c00, c01);
        bcc[1] = pack8(c10, c11);
    } else {
#pragma unroll
        for (int j = 0; j < 8; ++j) { bcc[0][j] = 0; bcc[1][j] = 0; }
    }

    // ---- matmul1: h stripe = relu(Wa[16w..16w+15,:] @ cc^T + ba stripe) ----
    f32x4 acc = (f32x4){0.f, 0.f, 0.f, 0.f};
    acc = __builtin_amdgcn_mfma_f32_16x16x32_bf16(frA[0], bcc[0], acc, 0, 0, 0);
    acc = __builtin_amdgcn_mfma_f32_16x16x32_bf16(frA[1], bcc[1], acc, 0, 0, 0);

    // ---- bias + relu + bf16, transpose into shared hT ----
    {
        u16 h0 = f2bf_rne(fmaxf(acc[0] + bav.x, 0.f));
        u16 h1 = f2bf_rne(fmaxf(acc[1] + bav.y, 0.f));
        u16 h2 = f2bf_rne(fmaxf(acc[2] + bav.z, 0.f));
        u16 h3 = f2bf_rne(fmaxf(acc[3] + bav.w, 0.f));
        uint2 pk; pk.x = (u32)h0 | ((u32)h1 << 16); pk.y = (u32)h2 | ((u32)h3 << 16);
        *(uint2*)(&hT[lc * HSTR + 16 * w + quad * 4]) = pk;
    }

    // ---- pack Wb fragments (loads arrived under matmul1/transpose) ----
    bf16x8 frB[2];
    frB[0] = pack8(b00, b01);
    frB[1] = pack8(b10, b11);

    __syncthreads();   // full h visible to all waves

    bf16x8 bh[2];
#pragma unroll
    for (int kt = 0; kt < 2; ++kt)
        bh[kt] = *(const bf16x8*)(&hT[lc * HSTR + kt * 32 + quad * 8]);

    // ---- matmul2: out stripe = Wb[16w..16w+15,:] @ h^T ----
    f32x4 acc2 = (f32x4){0.f, 0.f, 0.f, 0.f};
    acc2 = __builtin_amdgcn_mfma_f32_16x16x32_bf16(frB[0], bh[0], acc2, 0, 0, 0);
    acc2 = __builtin_amdgcn_mfma_f32_16x16x32_bf16(frB[1], bh[1], acc2, 0, 0, 0);

    // ---- max over clusters (cols lc<NCLU), then + bb ----
    const float NEG = -3.0e38f;
#pragma unroll
    for (int r = 0; r < 4; ++r) {
        float v = (lc < NCLU) ? acc2[r] : NEG;
#pragma unroll
        for (int off = 1; off < 16; off <<= 1)
            v = fmaxf(v, __shfl_xor(v, off));
        acc2[r] = v;
    }

    if (lc < 4) {
        int row = 16 * w + 4 * quad + lc;
        out[s * 64 + row] = acc2[lc] + bb[s * 64 + row];
    }
}

extern "C" void kernel_launch(void* const* d_in, const int* in_sizes, int n_in,
                              void* d_out, int out_size, void* d_ws, size_t ws_size,
                              hipStream_t stream) {
    const float* cc0  = (const float*)d_in[0];
    const float* Wk   = (const float*)d_in[1];
    const float* bk   = (const float*)d_in[2];
    const float* Wq   = (const float*)d_in[3];
    const float* bq   = (const float*)d_in[4];
    const float* Wv   = (const float*)d_in[5];
    const float* bv   = (const float*)d_in[6];
    const float* ccg  = (const float*)d_in[7];
    const float* ccb  = (const float*)d_in[8];
    const float* Wih  = (const float*)d_in[9];
    const float* Whh  = (const float*)d_in[10];
    const float* bih  = (const float*)d_in[11];
    const float* bhh  = (const float*)d_in[12];
    const float* lng  = (const float*)d_in[13];
    const float* lnb  = (const float*)d_in[14];
    const float* W1   = (const float*)d_in[15];
    const float* b1   = (const float*)d_in[16];
    const float* W2   = (const float*)d_in[17];
    const float* b2   = (const float*)d_in[18];
    const float* Wa   = (const float*)d_in[19];
    const float* ba   = (const float*)d_in[20];
    const float* Wb   = (const float*)d_in[21];
    const float* bb   = (const float*)d_in[22];

    float* cc_ws = (float*)d_ws;     // 640 floats
    float* out   = (float*)d_out;

    hipLaunchKernelGGL(phase1_kernel, dim3(1), dim3(640), 0, stream,
                       cc0, Wk, bk, Wq, bq, Wv, bv, ccg, ccb,
                       Wih, Whh, bih, bhh, lng, lnb, W1, b1, W2, b2, cc_ws);

    hipLaunchKernelGGL(phase2_kernel, dim3(NSLOT), dim3(256), 0, stream,
                       Wa, ba, Wb, bb, cc_ws, out);
}